// Round 1
// baseline (289.645 us; speedup 1.0000x reference)
//
#include <hip/hip_runtime.h>
#include <math.h>

#define B_ 16
#define L_ 256
#define D_ 64

// fast tanh: overflow-safe, ~1e-7 rel error (threshold is 1e-2)
__device__ __forceinline__ float ftanh(float x) {
    float ax = fabsf(x);
    float e  = __expf(-2.0f * ax);                       // in (0,1]
    float r  = (1.0f - e) * __builtin_amdgcn_rcpf(1.0f + e);
    return copysignf(r, x);
}

// Generic conv "level" pass: compute H[b,t, i0 .. i0+nrows) for ALL (b,t).
// Output row i reads concat rows 2i-1..2i+1: rows <64 come from X (time t),
// rows >=64 come from H (time t-1, zeros at t==0). Level structure guarantees
// all H rows read here were written by earlier passes (no intra-pass race).
__global__ void conv_pass(const float* __restrict__ X,
                          float* __restrict__ H,
                          const float* __restrict__ Wl,   // 9 floats (this layer)
                          const float* __restrict__ bl,   // 1 float  (this layer)
                          int i0, int nrows) {
    int idx = blockIdx.x * blockDim.x + threadIdx.x;
    int total = B_ * L_ * nrows * D_;
    if (idx >= total) return;

    int j  = idx & (D_ - 1);
    int r  = (idx >> 6) % nrows;          // nrows is a power of two
    int bt = idx / (D_ * nrows);
    int t  = bt & (L_ - 1);
    int b  = bt >> 8;                      // L_ == 256
    int i  = i0 + r;

    const float* xbase = X + (size_t)(b * L_ + t) * (D_ * D_);
    const float* hbase = H + (size_t)(b * L_ + (t - 1)) * (D_ * D_);

    float sum = bl[0];
#pragma unroll
    for (int ki = 0; ki < 3; ++ki) {
        int cr = 2 * i - 1 + ki;           // concat row (0..127), -1 = pad
#pragma unroll
        for (int kj = 0; kj < 3; ++kj) {
            int c = j - 1 + kj;
            if (c < 0 || c >= D_) continue;  // column zero-pad
            float v = 0.0f;
            if (cr >= 0) {
                if (cr < D_)      v = xbase[cr * D_ + c];
                else if (t > 0)   v = hbase[(cr - D_) * D_ + c];
            }
            sum = fmaf(Wl[ki * 3 + kj], v, sum);
        }
    }
    H[((size_t)(b * L_ + t) * D_ + i) * D_ + j] = ftanh(sum);
}

// Partial sums for the recurrent row 63: contributions from h_{t-1} rows 61,62
// (W rows 0,1) + bias, stored INTO the row-63 slot (scan finishes it in place).
__global__ void partial63(float* __restrict__ H,
                          const float* __restrict__ Wl,
                          const float* __restrict__ bl) {
    int idx = blockIdx.x * blockDim.x + threadIdx.x;
    if (idx >= B_ * L_ * D_) return;
    int j = idx & 63;
    int t = (idx >> 6) & (L_ - 1);
    int b = idx >> 14;                     // 64*256 = 2^14

    float sum = bl[0];
    if (t > 0) {
        const float* hb = H + (size_t)(b * L_ + (t - 1)) * (D_ * D_);
#pragma unroll
        for (int ki = 0; ki < 2; ++ki) {   // h rows 61 (W row 0), 62 (W row 1)
#pragma unroll
            for (int kj = 0; kj < 3; ++kj) {
                int c = j - 1 + kj;
                if (c < 0 || c >= D_) continue;
                sum = fmaf(Wl[ki * 3 + kj], hb[(61 + ki) * D_ + c], sum);
            }
        }
    }
    H[((size_t)(b * L_ + t) * D_ + 63) * D_ + j] = sum;  // partial, no tanh
}

// Sequential scan for row 63: one wave (64 lanes = 64 columns) per batch.
// s_t[j] = tanh(partial_t[j] + w6*s_{t-1}[j-1] + w7*s_{t-1}[j] + w8*s_{t-1}[j+1])
__global__ void scan63(float* __restrict__ H, const float* __restrict__ Wl) {
    int b = blockIdx.x;
    int j = threadIdx.x;                   // 0..63, exactly one wave
    float w6 = Wl[6], w7 = Wl[7], w8 = Wl[8];

    float* row = H + ((size_t)(b * L_) * D_ + 63) * D_ + j;
    const size_t ST = (size_t)D_ * D_;     // stride between timesteps

    float s = 0.0f;                        // h_{-1} row 63 == 0
    // 4-deep prefetch of partials (independent of the recurrence)
    float p0 = row[0 * ST], p1 = row[1 * ST], p2 = row[2 * ST], p3 = row[3 * ST];

#define STEP63(P, T)                                            \
    {                                                           \
        float ls = __shfl_up(s, 1);  if (j == 0)  ls = 0.0f;    \
        float rs = __shfl_down(s, 1); if (j == 63) rs = 0.0f;   \
        float z = P + w6 * ls + w7 * s + w8 * rs;               \
        s = ftanh(z);                                           \
        row[(size_t)(T) * ST] = s;                              \
    }

    for (int t = 0; t < L_; t += 4) {
        STEP63(p0, t + 0); if (t + 4 < L_) p0 = row[(size_t)(t + 4) * ST];
        STEP63(p1, t + 1); if (t + 5 < L_) p1 = row[(size_t)(t + 5) * ST];
        STEP63(p2, t + 2); if (t + 6 < L_) p2 = row[(size_t)(t + 6) * ST];
        STEP63(p3, t + 3); if (t + 7 < L_) p3 = row[(size_t)(t + 7) * ST];
    }
#undef STEP63
}

extern "C" void kernel_launch(void* const* d_in, const int* in_sizes, int n_in,
                              void* d_out, int out_size, void* d_ws, size_t ws_size,
                              hipStream_t stream) {
    const float* x    = (const float*)d_in[0];   // (B,L,D,D)
    const float* W    = (const float*)d_in[1];   // (2,1,1,3,3)
    const float* bias = (const float*)d_in[2];   // (2,)
    float* out = (float*)d_out;                  // layer-2 hidden states
    float* h1  = (float*)d_ws;                   // layer-1 hidden states (64 MiB)

    static const int lvl[6][2] = {{0,32},{32,16},{48,8},{56,4},{60,2},{62,1}};

    for (int l = 0; l < 2; ++l) {
        const float* X = (l == 0) ? x  : h1;
        float*       H = (l == 0) ? h1 : out;
        const float* Wl = W + l * 9;
        const float* bl = bias + l;

        for (int k = 0; k < 6; ++k) {
            int total = B_ * L_ * lvl[k][1] * D_;
            conv_pass<<<(total + 255) / 256, 256, 0, stream>>>(
                X, H, Wl, bl, lvl[k][0], lvl[k][1]);
        }
        {
            int total = B_ * L_ * D_;
            partial63<<<(total + 255) / 256, 256, 0, stream>>>(H, Wl, bl);
        }
        scan63<<<B_, 64, 0, stream>>>(H, Wl);
    }
}